// Round 5
// baseline (229.118 us; speedup 1.0000x reference)
//
#include <hip/hip_runtime.h>

#define D 64

// ---------------- CSR build ----------------

__global__ void k_hist(const int* __restrict__ dst, int* __restrict__ cnt, int e) {
    int i = blockIdx.x * blockDim.x + threadIdx.x;
    if (i < e) atomicAdd(&cnt[dst[i]], 1);
}

__global__ void k_scan1(const int* __restrict__ cnt, int* __restrict__ rowptr,
                        int* __restrict__ bsums, int n) {
    __shared__ int lds[256];
    int tid = threadIdx.x;
    int base = blockIdx.x * 2048 + tid * 8;
    int v[8];
    int s = 0;
#pragma unroll
    for (int j = 0; j < 8; ++j) {
        int idx = base + j;
        v[j] = (idx < n) ? cnt[idx] : 0;
        s += v[j];
    }
    lds[tid] = s;
    __syncthreads();
    for (int off = 1; off < 256; off <<= 1) {
        int t = (tid >= off) ? lds[tid - off] : 0;
        __syncthreads();
        lds[tid] += t;
        __syncthreads();
    }
    int run = lds[tid] - s;
#pragma unroll
    for (int j = 0; j < 8; ++j) {
        int idx = base + j;
        if (idx < n) rowptr[idx] = run;
        run += v[j];
    }
    if (tid == 255) bsums[blockIdx.x] = lds[255];
}

__global__ void k_scan2(int* __restrict__ rowptr, int* __restrict__ cursor,
                        float* __restrict__ dinv, const int* __restrict__ cnt,
                        const int* __restrict__ bsums, int n, int nb) {
    __shared__ int s_off;
    int i = blockIdx.x * blockDim.x + threadIdx.x;
    int b = (blockIdx.x * blockDim.x) >> 11;
    if (threadIdx.x == 0) {
        int o = 0;
        for (int j = 0; j < b; ++j) o += bsums[j];
        s_off = o;
    }
    __syncthreads();
    if (i < n) {
        int rp = rowptr[i] + s_off;
        rowptr[i] = rp;
        cursor[i] = rp;
        dinv[i] = rsqrtf((float)(cnt[i] + 1));
    }
    if (blockIdx.x == 0 && threadIdx.x == 0) {
        int t = 0;
        for (int j = 0; j < nb; ++j) t += bsums[j];
        rowptr[n] = t;
    }
}

// Scatter src into CSR order. The value store is an atomicExch so the 4B write
// resolves at the device-coherent point instead of dirtying a private-L2 line
// (plain stores showed 16x write amplification: 52 MB for 3.2 MB of payload).
__global__ void k_fill(const int* __restrict__ src, const int* __restrict__ dst,
                       int* __restrict__ cursor, int* __restrict__ csr, int e) {
    int i = blockIdx.x * blockDim.x + threadIdx.x;
    if (i < e) {
        int d = dst[i];
        int pos = atomicAdd(&cursor[d], 1);
        atomicExch(&csr[pos], src[i]);
    }
}

// ---------------- compute ----------------

// G[r][c] = dinv[r] * sum_k X[r][k] * W[k][c]
// Persistent blocks; 16 rows per tile; thread = (row_local = tid>>4, c4 = tid&15).
__global__ __launch_bounds__(256) void k_gemm2(const float* __restrict__ X,
                                               const float* __restrict__ W,
                                               const float* __restrict__ dinv,
                                               float* __restrict__ G, int n, int ntiles) {
    __shared__ float Ws[D][D];       // 16 KB
    __shared__ float Xs[16][D + 4];  // padded -> conflict-free
    int tid = threadIdx.x;
    int rl = tid >> 4;   // 0..15
    int c4 = tid & 15;   // 0..15

    for (int i = tid; i < (D * D) / 4; i += 256)
        reinterpret_cast<float4*>(&Ws[0][0])[i] = reinterpret_cast<const float4*>(W)[i];

    for (int tile = blockIdx.x; tile < ntiles; tile += gridDim.x) {
        int rowbase = tile * 16;
        int row = rowbase + rl;
        __syncthreads();
        {
            float4 v = make_float4(0.f, 0.f, 0.f, 0.f);
            if (row < n) v = reinterpret_cast<const float4*>(X)[(size_t)row * 16 + c4];
            *reinterpret_cast<float4*>(&Xs[rl][c4 * 4]) = v;
        }
        __syncthreads();

        float4 acc = make_float4(0.f, 0.f, 0.f, 0.f);
#pragma unroll
        for (int k = 0; k < D; ++k) {
            float xk = Xs[rl][k];
            float4 w = *reinterpret_cast<const float4*>(&Ws[k][c4 * 4]);
            acc.x += xk * w.x;
            acc.y += xk * w.y;
            acc.z += xk * w.z;
            acc.w += xk * w.w;
        }
        if (row < n) {
            float dv = dinv[row];
            acc.x *= dv; acc.y *= dv; acc.z *= dv; acc.w *= dv;
            reinterpret_cast<float4*>(G)[(size_t)row * 16 + c4] = acc;
        }
    }
}

// out[i] = dinv[i]*(G[i] + sum_{src in row i} G[src]) + b ; optional relu.
// One wave per row; lane = (eq = lane>>4 edge subgroup, c4 = lane&15 column quad).
__global__ __launch_bounds__(256) void k_agg2(const float* __restrict__ G,
                                              const int* __restrict__ rowptr,
                                              const int* __restrict__ csr,
                                              const float* __restrict__ dinv,
                                              const float* __restrict__ bias,
                                              float* __restrict__ out,
                                              int n, int do_relu) {
    int wid = (blockIdx.x * blockDim.x + threadIdx.x) >> 6;
    if (wid >= n) return;
    int lane = threadIdx.x & 63;
    int eq = lane >> 4;
    int c4 = lane & 15;
    int beg = rowptr[wid];
    int end = rowptr[wid + 1];

    float4 acc = make_float4(0.f, 0.f, 0.f, 0.f);
    for (int e = beg + eq; e < end; e += 4) {
        int s = __builtin_nontemporal_load(&csr[e]);  // streamed once; don't evict G from L2
        float4 v = reinterpret_cast<const float4*>(G)[(size_t)s * 16 + c4];
        acc.x += v.x; acc.y += v.y; acc.z += v.z; acc.w += v.w;
    }
#pragma unroll
    for (int off = 16; off < 64; off <<= 1) {
        acc.x += __shfl_xor(acc.x, off);
        acc.y += __shfl_xor(acc.y, off);
        acc.z += __shfl_xor(acc.z, off);
        acc.w += __shfl_xor(acc.w, off);
    }
    if (eq == 0) {
        float4 s4 = reinterpret_cast<const float4*>(G)[(size_t)wid * 16 + c4];
        float dv = dinv[wid];
        float4 b4 = reinterpret_cast<const float4*>(bias)[c4];
        float4 o;
        o.x = (acc.x + s4.x) * dv + b4.x;
        o.y = (acc.y + s4.y) * dv + b4.y;
        o.z = (acc.z + s4.z) * dv + b4.z;
        o.w = (acc.w + s4.w) * dv + b4.w;
        if (do_relu) {
            o.x = fmaxf(o.x, 0.f); o.y = fmaxf(o.y, 0.f);
            o.z = fmaxf(o.z, 0.f); o.w = fmaxf(o.w, 0.f);
        }
        reinterpret_cast<float4*>(out)[(size_t)wid * 16 + c4] = o;
    }
}

// ---------------- launch ----------------

extern "C" void kernel_launch(void* const* d_in, const int* in_sizes, int n_in,
                              void* d_out, int out_size, void* d_ws, size_t ws_size,
                              hipStream_t stream) {
    const int* ei = (const int*)d_in[0];
    const float* emb = (const float*)d_in[1];
    const float* W1 = (const float*)d_in[2];
    const float* b1 = (const float*)d_in[3];
    const float* W2 = (const float*)d_in[4];
    const float* b2 = (const float*)d_in[5];
    float* out = (float*)d_out;

    int E = in_sizes[0] / 2;
    int N = in_sizes[1] / D;
    const int* src = ei;
    const int* dst = ei + E;

    auto al = [](size_t x) { return (x + 255) & ~(size_t)255; };
    char* ws = (char*)d_ws;
    size_t off = 0;
    int* cnt = (int*)(ws + off);      off = al(off + (size_t)N * 4);
    int* rowptr = (int*)(ws + off);   off = al(off + ((size_t)N + 1) * 4);
    int* cursor = (int*)(ws + off);   off = al(off + (size_t)N * 4);
    int* bsums = (int*)(ws + off);    off = al(off + 64 * 4);
    int* csr = (int*)(ws + off);      off = al(off + (size_t)E * 4);
    float* dinv = (float*)(ws + off); off = al(off + (size_t)N * 4);
    float* g = (float*)(ws + off);    off = al(off + (size_t)N * D * 4);
    float* x = out;  // reuse d_out as the layer-1 activation buffer

    int nb_scan = (N + 2047) / 2048;
    int ntiles = (N + 15) / 16;
    int gemm_blocks = 1024;

    hipMemsetAsync(cnt, 0, (size_t)N * 4, stream);
    hipLaunchKernelGGL(k_hist, dim3((E + 255) / 256), dim3(256), 0, stream, dst, cnt, E);
    hipLaunchKernelGGL(k_scan1, dim3(nb_scan), dim3(256), 0, stream, cnt, rowptr, bsums, N);
    hipLaunchKernelGGL(k_scan2, dim3((N + 255) / 256), dim3(256), 0, stream,
                       rowptr, cursor, dinv, cnt, bsums, N, nb_scan);
    hipLaunchKernelGGL(k_fill, dim3((E + 255) / 256), dim3(256), 0, stream,
                       src, dst, cursor, csr, E);

    // layer 1
    hipLaunchKernelGGL(k_gemm2, dim3(gemm_blocks), dim3(256), 0, stream,
                       emb, W1, dinv, g, N, ntiles);
    hipLaunchKernelGGL(k_agg2, dim3((N + 3) / 4), dim3(256), 0, stream,
                       g, rowptr, csr, dinv, b1, x, N, 1);

    // layer 2
    hipLaunchKernelGGL(k_gemm2, dim3(gemm_blocks), dim3(256), 0, stream,
                       x, W2, dinv, g, N, ntiles);
    hipLaunchKernelGGL(k_agg2, dim3((N + 3) / 4), dim3(256), 0, stream,
                       g, rowptr, csr, dinv, b2, out, N, 0);
}

// Round 6
// 201.293 us; speedup vs baseline: 1.1382x; 1.1382x over previous
//
#include <hip/hip_runtime.h>

#define D 64

// ---------------- CSR build ----------------
// k_hist / k_fill partition the dst space 8 ways by blockIdx.x&7. With
// round-robin block->XCD dispatch, all writers of a given cnt/csr line sit on
// one XCD, so stores merge in that L2 instead of bouncing line ownership
// across XCDs (measured: unpartitioned scatter = 64B writeback per 4B store).

__global__ __launch_bounds__(256) void k_hist(const int* __restrict__ dst,
                                              int* __restrict__ cnt, int e, int n) {
    int r = blockIdx.x & 7;
    int lo = (int)(((long long)r * n) >> 3);
    int hi = (int)(((long long)(r + 1) * n) >> 3);
    int nch = gridDim.x >> 3;
    int chunk = blockIdx.x >> 3;
    for (int i = chunk * blockDim.x + threadIdx.x; i < e; i += nch * blockDim.x) {
        int d = dst[i];
        if (d >= lo && d < hi) atomicAdd(&cnt[d], 1);
    }
}

__global__ void k_scan1(const int* __restrict__ cnt, int* __restrict__ rowptr,
                        int* __restrict__ bsums, int n) {
    __shared__ int lds[256];
    int tid = threadIdx.x;
    int base = blockIdx.x * 2048 + tid * 8;
    int v[8];
    int s = 0;
#pragma unroll
    for (int j = 0; j < 8; ++j) {
        int idx = base + j;
        v[j] = (idx < n) ? cnt[idx] : 0;
        s += v[j];
    }
    lds[tid] = s;
    __syncthreads();
    for (int off = 1; off < 256; off <<= 1) {
        int t = (tid >= off) ? lds[tid - off] : 0;
        __syncthreads();
        lds[tid] += t;
        __syncthreads();
    }
    int run = lds[tid] - s;
#pragma unroll
    for (int j = 0; j < 8; ++j) {
        int idx = base + j;
        if (idx < n) rowptr[idx] = run;
        run += v[j];
    }
    if (tid == 255) bsums[blockIdx.x] = lds[255];
}

__global__ void k_scan2(int* __restrict__ rowptr, int* __restrict__ cursor,
                        float* __restrict__ dinv, const int* __restrict__ cnt,
                        const int* __restrict__ bsums, int n, int nb) {
    __shared__ int s_off;
    int i = blockIdx.x * blockDim.x + threadIdx.x;
    int b = (blockIdx.x * blockDim.x) >> 11;
    if (threadIdx.x == 0) {
        int o = 0;
        for (int j = 0; j < b; ++j) o += bsums[j];
        s_off = o;
    }
    __syncthreads();
    if (i < n) {
        int rp = rowptr[i] + s_off;
        rowptr[i] = rp;
        cursor[i] = rp;
        dinv[i] = rsqrtf((float)(cnt[i] + 1));
    }
    if (blockIdx.x == 0 && threadIdx.x == 0) {
        int t = 0;
        for (int j = 0; j < nb; ++j) t += bsums[j];
        rowptr[n] = t;
    }
}

__global__ __launch_bounds__(256) void k_fill(const int* __restrict__ src,
                                              const int* __restrict__ dst,
                                              int* __restrict__ cursor,
                                              int* __restrict__ csr, int e, int n) {
    int r = blockIdx.x & 7;
    int lo = (int)(((long long)r * n) >> 3);
    int hi = (int)(((long long)(r + 1) * n) >> 3);
    int nch = gridDim.x >> 3;
    int chunk = blockIdx.x >> 3;
    for (int i = chunk * blockDim.x + threadIdx.x; i < e; i += nch * blockDim.x) {
        int d = dst[i];
        if (d >= lo && d < hi) {
            int pos = atomicAdd(&cursor[d], 1);
            csr[pos] = src[i];
        }
    }
}

// ---------------- compute ----------------

// G[r][c] = dinv[r] * sum_k X[r][k] * W[k][c]
__global__ __launch_bounds__(256) void k_gemm2(const float* __restrict__ X,
                                               const float* __restrict__ W,
                                               const float* __restrict__ dinv,
                                               float* __restrict__ G, int n, int ntiles) {
    __shared__ float Ws[D][D];       // 16 KB
    __shared__ float Xs[16][D + 4];  // padded -> conflict-free
    int tid = threadIdx.x;
    int rl = tid >> 4;   // 0..15
    int c4 = tid & 15;   // 0..15

    for (int i = tid; i < (D * D) / 4; i += 256)
        reinterpret_cast<float4*>(&Ws[0][0])[i] = reinterpret_cast<const float4*>(W)[i];

    for (int tile = blockIdx.x; tile < ntiles; tile += gridDim.x) {
        int rowbase = tile * 16;
        int row = rowbase + rl;
        __syncthreads();
        {
            float4 v = make_float4(0.f, 0.f, 0.f, 0.f);
            if (row < n) v = reinterpret_cast<const float4*>(X)[(size_t)row * 16 + c4];
            *reinterpret_cast<float4*>(&Xs[rl][c4 * 4]) = v;
        }
        __syncthreads();

        float4 acc = make_float4(0.f, 0.f, 0.f, 0.f);
#pragma unroll
        for (int k = 0; k < D; ++k) {
            float xk = Xs[rl][k];
            float4 w = *reinterpret_cast<const float4*>(&Ws[k][c4 * 4]);
            acc.x += xk * w.x;
            acc.y += xk * w.y;
            acc.z += xk * w.z;
            acc.w += xk * w.w;
        }
        if (row < n) {
            float dv = dinv[row];
            acc.x *= dv; acc.y *= dv; acc.z *= dv; acc.w *= dv;
            reinterpret_cast<float4*>(G)[(size_t)row * 16 + c4] = acc;
        }
    }
}

// out[i] = dinv[i]*(G[i] + sum_{src in row i} G[src]) + b ; optional relu.
__global__ __launch_bounds__(256) void k_agg2(const float* __restrict__ G,
                                              const int* __restrict__ rowptr,
                                              const int* __restrict__ csr,
                                              const float* __restrict__ dinv,
                                              const float* __restrict__ bias,
                                              float* __restrict__ out,
                                              int n, int do_relu) {
    int wid = (blockIdx.x * blockDim.x + threadIdx.x) >> 6;
    if (wid >= n) return;
    int lane = threadIdx.x & 63;
    int eq = lane >> 4;
    int c4 = lane & 15;
    int beg = rowptr[wid];
    int end = rowptr[wid + 1];

    float4 acc = make_float4(0.f, 0.f, 0.f, 0.f);
    for (int e = beg + eq; e < end; e += 4) {
        int s = __builtin_nontemporal_load(&csr[e]);
        float4 v = reinterpret_cast<const float4*>(G)[(size_t)s * 16 + c4];
        acc.x += v.x; acc.y += v.y; acc.z += v.z; acc.w += v.w;
    }
#pragma unroll
    for (int off = 16; off < 64; off <<= 1) {
        acc.x += __shfl_xor(acc.x, off);
        acc.y += __shfl_xor(acc.y, off);
        acc.z += __shfl_xor(acc.z, off);
        acc.w += __shfl_xor(acc.w, off);
    }
    if (eq == 0) {
        float4 s4 = reinterpret_cast<const float4*>(G)[(size_t)wid * 16 + c4];
        float dv = dinv[wid];
        float4 b4 = reinterpret_cast<const float4*>(bias)[c4];
        float4 o;
        o.x = (acc.x + s4.x) * dv + b4.x;
        o.y = (acc.y + s4.y) * dv + b4.y;
        o.z = (acc.z + s4.z) * dv + b4.z;
        o.w = (acc.w + s4.w) * dv + b4.w;
        if (do_relu) {
            o.x = fmaxf(o.x, 0.f); o.y = fmaxf(o.y, 0.f);
            o.z = fmaxf(o.z, 0.f); o.w = fmaxf(o.w, 0.f);
        }
        reinterpret_cast<float4*>(out)[(size_t)wid * 16 + c4] = o;
    }
}

// ---------------- launch ----------------

extern "C" void kernel_launch(void* const* d_in, const int* in_sizes, int n_in,
                              void* d_out, int out_size, void* d_ws, size_t ws_size,
                              hipStream_t stream) {
    const int* ei = (const int*)d_in[0];
    const float* emb = (const float*)d_in[1];
    const float* W1 = (const float*)d_in[2];
    const float* b1 = (const float*)d_in[3];
    const float* W2 = (const float*)d_in[4];
    const float* b2 = (const float*)d_in[5];
    float* out = (float*)d_out;

    int E = in_sizes[0] / 2;
    int N = in_sizes[1] / D;
    const int* src = ei;
    const int* dst = ei + E;

    auto al = [](size_t x) { return (x + 255) & ~(size_t)255; };
    char* ws = (char*)d_ws;
    size_t off = 0;
    int* cnt = (int*)(ws + off);      off = al(off + (size_t)N * 4);
    int* rowptr = (int*)(ws + off);   off = al(off + ((size_t)N + 1) * 4);
    int* cursor = (int*)(ws + off);   off = al(off + (size_t)N * 4);
    int* bsums = (int*)(ws + off);    off = al(off + 64 * 4);
    int* csr = (int*)(ws + off);      off = al(off + (size_t)E * 4);
    float* dinv = (float*)(ws + off); off = al(off + (size_t)N * 4);
    float* g = (float*)(ws + off);    off = al(off + (size_t)N * D * 4);
    float* x = out;  // reuse d_out as the layer-1 activation buffer

    int nb_scan = (N + 2047) / 2048;
    int ntiles = (N + 15) / 16;
    int gemm_blocks = 1024;
    int part_blocks = 1024;  // 8 ranges x 128 chunks

    hipMemsetAsync(cnt, 0, (size_t)N * 4, stream);
    hipLaunchKernelGGL(k_hist, dim3(part_blocks), dim3(256), 0, stream, dst, cnt, E, N);
    hipLaunchKernelGGL(k_scan1, dim3(nb_scan), dim3(256), 0, stream, cnt, rowptr, bsums, N);
    hipLaunchKernelGGL(k_scan2, dim3((N + 255) / 256), dim3(256), 0, stream,
                       rowptr, cursor, dinv, cnt, bsums, N, nb_scan);
    hipLaunchKernelGGL(k_fill, dim3(part_blocks), dim3(256), 0, stream,
                       src, dst, cursor, csr, E, N);

    // layer 1
    hipLaunchKernelGGL(k_gemm2, dim3(gemm_blocks), dim3(256), 0, stream,
                       emb, W1, dinv, g, N, ntiles);
    hipLaunchKernelGGL(k_agg2, dim3((N + 3) / 4), dim3(256), 0, stream,
                       g, rowptr, csr, dinv, b1, x, N, 1);

    // layer 2
    hipLaunchKernelGGL(k_gemm2, dim3(gemm_blocks), dim3(256), 0, stream,
                       x, W2, dinv, g, N, ntiles);
    hipLaunchKernelGGL(k_agg2, dim3((N + 3) / 4), dim3(256), 0, stream,
                       g, rowptr, csr, dinv, b2, out, N, 0);
}

// Round 7
// 200.311 us; speedup vs baseline: 1.1438x; 1.0049x over previous
//
#include <hip/hip_runtime.h>

#define D 64

// ---------------- CSR build ----------------
// k_hist / k_fill partition the dst space 8 ways by blockIdx.x&7. With
// round-robin block->XCD dispatch, all writers of a given cnt/csr line sit on
// one XCD, so stores merge in that L2 instead of bouncing line ownership
// across XCDs (measured: unpartitioned scatter = 64B writeback per 4B store;
// partitioned: k_hist/k_fill dropped out of the top-5 entirely).

// Grid-stride int4 zero: the rocclr fillBufferAligned memset was 45 us (!)
// for 200 KB (tiny latency-bound grid); this is ~2 us.
__global__ __launch_bounds__(256) void k_zero(int* __restrict__ p, int n4) {
    int stride = gridDim.x * blockDim.x;
    for (int i = blockIdx.x * blockDim.x + threadIdx.x; i < n4; i += stride)
        reinterpret_cast<int4*>(p)[i] = make_int4(0, 0, 0, 0);
}

__global__ __launch_bounds__(256) void k_hist(const int* __restrict__ dst,
                                              int* __restrict__ cnt, int e, int n) {
    int r = blockIdx.x & 7;
    int lo = (int)(((long long)r * n) >> 3);
    int hi = (int)(((long long)(r + 1) * n) >> 3);
    int nch = gridDim.x >> 3;
    int chunk = blockIdx.x >> 3;
    for (int i = chunk * blockDim.x + threadIdx.x; i < e; i += nch * blockDim.x) {
        int d = dst[i];
        if (d >= lo && d < hi) atomicAdd(&cnt[d], 1);
    }
}

__global__ void k_scan1(const int* __restrict__ cnt, int* __restrict__ rowptr,
                        int* __restrict__ bsums, int n) {
    __shared__ int lds[256];
    int tid = threadIdx.x;
    int base = blockIdx.x * 2048 + tid * 8;
    int v[8];
    int s = 0;
#pragma unroll
    for (int j = 0; j < 8; ++j) {
        int idx = base + j;
        v[j] = (idx < n) ? cnt[idx] : 0;
        s += v[j];
    }
    lds[tid] = s;
    __syncthreads();
    for (int off = 1; off < 256; off <<= 1) {
        int t = (tid >= off) ? lds[tid - off] : 0;
        __syncthreads();
        lds[tid] += t;
        __syncthreads();
    }
    int run = lds[tid] - s;
#pragma unroll
    for (int j = 0; j < 8; ++j) {
        int idx = base + j;
        if (idx < n) rowptr[idx] = run;
        run += v[j];
    }
    if (tid == 255) bsums[blockIdx.x] = lds[255];
}

__global__ void k_scan2(int* __restrict__ rowptr, int* __restrict__ cursor,
                        float* __restrict__ dinv, const int* __restrict__ cnt,
                        const int* __restrict__ bsums, int n, int nb) {
    __shared__ int s_off;
    int i = blockIdx.x * blockDim.x + threadIdx.x;
    int b = (blockIdx.x * blockDim.x) >> 11;
    if (threadIdx.x == 0) {
        int o = 0;
        for (int j = 0; j < b; ++j) o += bsums[j];
        s_off = o;
    }
    __syncthreads();
    if (i < n) {
        int rp = rowptr[i] + s_off;
        rowptr[i] = rp;
        cursor[i] = rp;
        dinv[i] = rsqrtf((float)(cnt[i] + 1));
    }
    if (blockIdx.x == 0 && threadIdx.x == 0) {
        int t = 0;
        for (int j = 0; j < nb; ++j) t += bsums[j];
        rowptr[n] = t;
    }
}

__global__ __launch_bounds__(256) void k_fill(const int* __restrict__ src,
                                              const int* __restrict__ dst,
                                              int* __restrict__ cursor,
                                              int* __restrict__ csr, int e, int n) {
    int r = blockIdx.x & 7;
    int lo = (int)(((long long)r * n) >> 3);
    int hi = (int)(((long long)(r + 1) * n) >> 3);
    int nch = gridDim.x >> 3;
    int chunk = blockIdx.x >> 3;
    for (int i = chunk * blockDim.x + threadIdx.x; i < e; i += nch * blockDim.x) {
        int d = dst[i];
        if (d >= lo && d < hi) {
            int pos = atomicAdd(&cursor[d], 1);
            csr[pos] = src[i];
        }
    }
}

// ---------------- compute ----------------

// G[r][c] = dinv[r] * sum_k X[r][k] * W[k][c]
__global__ __launch_bounds__(256) void k_gemm2(const float* __restrict__ X,
                                               const float* __restrict__ W,
                                               const float* __restrict__ dinv,
                                               float* __restrict__ G, int n, int ntiles) {
    __shared__ float Ws[D][D];       // 16 KB
    __shared__ float Xs[16][D + 4];  // padded -> conflict-free
    int tid = threadIdx.x;
    int rl = tid >> 4;   // 0..15
    int c4 = tid & 15;   // 0..15

    for (int i = tid; i < (D * D) / 4; i += 256)
        reinterpret_cast<float4*>(&Ws[0][0])[i] = reinterpret_cast<const float4*>(W)[i];

    for (int tile = blockIdx.x; tile < ntiles; tile += gridDim.x) {
        int rowbase = tile * 16;
        int row = rowbase + rl;
        __syncthreads();
        {
            float4 v = make_float4(0.f, 0.f, 0.f, 0.f);
            if (row < n) v = reinterpret_cast<const float4*>(X)[(size_t)row * 16 + c4];
            *reinterpret_cast<float4*>(&Xs[rl][c4 * 4]) = v;
        }
        __syncthreads();

        float4 acc = make_float4(0.f, 0.f, 0.f, 0.f);
#pragma unroll
        for (int k = 0; k < D; ++k) {
            float xk = Xs[rl][k];
            float4 w = *reinterpret_cast<const float4*>(&Ws[k][c4 * 4]);
            acc.x += xk * w.x;
            acc.y += xk * w.y;
            acc.z += xk * w.z;
            acc.w += xk * w.w;
        }
        if (row < n) {
            float dv = dinv[row];
            acc.x *= dv; acc.y *= dv; acc.z *= dv; acc.w *= dv;
            reinterpret_cast<float4*>(G)[(size_t)row * 16 + c4] = acc;
        }
    }
}

// out[i] = dinv[i]*(G[i] + sum_{src in row i} G[src]) + b ; optional relu.
__global__ __launch_bounds__(256) void k_agg2(const float* __restrict__ G,
                                              const int* __restrict__ rowptr,
                                              const int* __restrict__ csr,
                                              const float* __restrict__ dinv,
                                              const float* __restrict__ bias,
                                              float* __restrict__ out,
                                              int n, int do_relu) {
    int wid = (blockIdx.x * blockDim.x + threadIdx.x) >> 6;
    if (wid >= n) return;
    int lane = threadIdx.x & 63;
    int eq = lane >> 4;
    int c4 = lane & 15;
    int beg = rowptr[wid];
    int end = rowptr[wid + 1];

    float4 acc = make_float4(0.f, 0.f, 0.f, 0.f);
    for (int e = beg + eq; e < end; e += 4) {
        int s = __builtin_nontemporal_load(&csr[e]);
        float4 v = reinterpret_cast<const float4*>(G)[(size_t)s * 16 + c4];
        acc.x += v.x; acc.y += v.y; acc.z += v.z; acc.w += v.w;
    }
#pragma unroll
    for (int off = 16; off < 64; off <<= 1) {
        acc.x += __shfl_xor(acc.x, off);
        acc.y += __shfl_xor(acc.y, off);
        acc.z += __shfl_xor(acc.z, off);
        acc.w += __shfl_xor(acc.w, off);
    }
    if (eq == 0) {
        float4 s4 = reinterpret_cast<const float4*>(G)[(size_t)wid * 16 + c4];
        float dv = dinv[wid];
        float4 b4 = reinterpret_cast<const float4*>(bias)[c4];
        float4 o;
        o.x = (acc.x + s4.x) * dv + b4.x;
        o.y = (acc.y + s4.y) * dv + b4.y;
        o.z = (acc.z + s4.z) * dv + b4.z;
        o.w = (acc.w + s4.w) * dv + b4.w;
        if (do_relu) {
            o.x = fmaxf(o.x, 0.f); o.y = fmaxf(o.y, 0.f);
            o.z = fmaxf(o.z, 0.f); o.w = fmaxf(o.w, 0.f);
        }
        reinterpret_cast<float4*>(out)[(size_t)wid * 16 + c4] = o;
    }
}

// ---------------- launch ----------------

extern "C" void kernel_launch(void* const* d_in, const int* in_sizes, int n_in,
                              void* d_out, int out_size, void* d_ws, size_t ws_size,
                              hipStream_t stream) {
    const int* ei = (const int*)d_in[0];
    const float* emb = (const float*)d_in[1];
    const float* W1 = (const float*)d_in[2];
    const float* b1 = (const float*)d_in[3];
    const float* W2 = (const float*)d_in[4];
    const float* b2 = (const float*)d_in[5];
    float* out = (float*)d_out;

    int E = in_sizes[0] / 2;
    int N = in_sizes[1] / D;
    const int* src = ei;
    const int* dst = ei + E;

    auto al = [](size_t x) { return (x + 255) & ~(size_t)255; };
    char* ws = (char*)d_ws;
    size_t off = 0;
    int* cnt = (int*)(ws + off);      off = al(off + (size_t)N * 4);
    int* rowptr = (int*)(ws + off);   off = al(off + ((size_t)N + 1) * 4);
    int* cursor = (int*)(ws + off);   off = al(off + (size_t)N * 4);
    int* bsums = (int*)(ws + off);    off = al(off + 64 * 4);
    int* csr = (int*)(ws + off);      off = al(off + (size_t)E * 4);
    float* dinv = (float*)(ws + off); off = al(off + (size_t)N * 4);
    float* g = (float*)(ws + off);    off = al(off + (size_t)N * D * 4);
    float* x = out;  // reuse d_out as the layer-1 activation buffer

    int nb_scan = (N + 2047) / 2048;
    int ntiles = (N + 15) / 16;
    int gemm_blocks = 1024;
    int part_blocks = 1024;  // 8 ranges x 128 chunks

    // N*4 bytes is a multiple of 16 for N=50000; round up defensively.
    hipLaunchKernelGGL(k_zero, dim3(512), dim3(256), 0, stream, cnt, (N + 3) / 4);
    hipLaunchKernelGGL(k_hist, dim3(part_blocks), dim3(256), 0, stream, dst, cnt, E, N);
    hipLaunchKernelGGL(k_scan1, dim3(nb_scan), dim3(256), 0, stream, cnt, rowptr, bsums, N);
    hipLaunchKernelGGL(k_scan2, dim3((N + 255) / 256), dim3(256), 0, stream,
                       rowptr, cursor, dinv, cnt, bsums, N, nb_scan);
    hipLaunchKernelGGL(k_fill, dim3(part_blocks), dim3(256), 0, stream,
                       src, dst, cursor, csr, E, N);

    // layer 1
    hipLaunchKernelGGL(k_gemm2, dim3(gemm_blocks), dim3(256), 0, stream,
                       emb, W1, dinv, g, N, ntiles);
    hipLaunchKernelGGL(k_agg2, dim3((N + 3) / 4), dim3(256), 0, stream,
                       g, rowptr, csr, dinv, b1, x, N, 1);

    // layer 2
    hipLaunchKernelGGL(k_gemm2, dim3(gemm_blocks), dim3(256), 0, stream,
                       x, W2, dinv, g, N, ntiles);
    hipLaunchKernelGGL(k_agg2, dim3((N + 3) / 4), dim3(256), 0, stream,
                       g, rowptr, csr, dinv, b2, out, N, 0);
}

// Round 8
// 192.960 us; speedup vs baseline: 1.1874x; 1.0381x over previous
//
#include <hip/hip_runtime.h>
#include <hip/hip_fp16.h>

#define D 64

// ---------------- CSR build ----------------
// k_hist / k_fill partition the dst space 8 ways by blockIdx.x&7 (XCD-local
// line ownership; unpartitioned scatter measured 64B writeback per 4B store).

__global__ __launch_bounds__(256) void k_zero(int* __restrict__ p, int n4) {
    int stride = gridDim.x * blockDim.x;
    for (int i = blockIdx.x * blockDim.x + threadIdx.x; i < n4; i += stride)
        reinterpret_cast<int4*>(p)[i] = make_int4(0, 0, 0, 0);
}

__global__ __launch_bounds__(256) void k_hist(const int* __restrict__ dst,
                                              int* __restrict__ cnt, int e, int n) {
    int r = blockIdx.x & 7;
    int lo = (int)(((long long)r * n) >> 3);
    int hi = (int)(((long long)(r + 1) * n) >> 3);
    int nch = gridDim.x >> 3;
    int chunk = blockIdx.x >> 3;
    for (int i = chunk * blockDim.x + threadIdx.x; i < e; i += nch * blockDim.x) {
        int d = dst[i];
        if (d >= lo && d < hi) atomicAdd(&cnt[d], 1);
    }
}

__global__ void k_scan1(const int* __restrict__ cnt, int* __restrict__ rowptr,
                        int* __restrict__ bsums, int n) {
    __shared__ int lds[256];
    int tid = threadIdx.x;
    int base = blockIdx.x * 2048 + tid * 8;
    int v[8];
    int s = 0;
#pragma unroll
    for (int j = 0; j < 8; ++j) {
        int idx = base + j;
        v[j] = (idx < n) ? cnt[idx] : 0;
        s += v[j];
    }
    lds[tid] = s;
    __syncthreads();
    for (int off = 1; off < 256; off <<= 1) {
        int t = (tid >= off) ? lds[tid - off] : 0;
        __syncthreads();
        lds[tid] += t;
        __syncthreads();
    }
    int run = lds[tid] - s;
#pragma unroll
    for (int j = 0; j < 8; ++j) {
        int idx = base + j;
        if (idx < n) rowptr[idx] = run;
        run += v[j];
    }
    if (tid == 255) bsums[blockIdx.x] = lds[255];
}

__global__ void k_scan2(int* __restrict__ rowptr, int* __restrict__ cursor,
                        float* __restrict__ dinv, const int* __restrict__ cnt,
                        const int* __restrict__ bsums, int n, int nb) {
    __shared__ int s_off;
    int i = blockIdx.x * blockDim.x + threadIdx.x;
    int b = (blockIdx.x * blockDim.x) >> 11;
    if (threadIdx.x == 0) {
        int o = 0;
        for (int j = 0; j < b; ++j) o += bsums[j];
        s_off = o;
    }
    __syncthreads();
    if (i < n) {
        int rp = rowptr[i] + s_off;
        rowptr[i] = rp;
        cursor[i] = rp;
        dinv[i] = rsqrtf((float)(cnt[i] + 1));
    }
    if (blockIdx.x == 0 && threadIdx.x == 0) {
        int t = 0;
        for (int j = 0; j < nb; ++j) t += bsums[j];
        rowptr[n] = t;
    }
}

__global__ __launch_bounds__(256) void k_fill(const int* __restrict__ src,
                                              const int* __restrict__ dst,
                                              int* __restrict__ cursor,
                                              int* __restrict__ csr, int e, int n) {
    int r = blockIdx.x & 7;
    int lo = (int)(((long long)r * n) >> 3);
    int hi = (int)(((long long)(r + 1) * n) >> 3);
    int nch = gridDim.x >> 3;
    int chunk = blockIdx.x >> 3;
    for (int i = chunk * blockDim.x + threadIdx.x; i < e; i += nch * blockDim.x) {
        int d = dst[i];
        if (d >= lo && d < hi) {
            int pos = atomicAdd(&cursor[d], 1);
            csr[pos] = src[i];
        }
    }
}

// ---------------- compute ----------------

// G[r][c] = (half) dinv[r] * sum_k X[r][k] * W[k][c]
// fp16 G halves the dominant gather traffic; accumulation stays fp32.
__global__ __launch_bounds__(256) void k_gemm2(const float* __restrict__ X,
                                               const float* __restrict__ W,
                                               const float* __restrict__ dinv,
                                               __half* __restrict__ G, int n, int ntiles) {
    __shared__ float Ws[D][D];       // 16 KB
    __shared__ float Xs[16][D + 4];  // padded -> conflict-free
    int tid = threadIdx.x;
    int rl = tid >> 4;   // 0..15
    int c4 = tid & 15;   // 0..15

    for (int i = tid; i < (D * D) / 4; i += 256)
        reinterpret_cast<float4*>(&Ws[0][0])[i] = reinterpret_cast<const float4*>(W)[i];

    for (int tile = blockIdx.x; tile < ntiles; tile += gridDim.x) {
        int rowbase = tile * 16;
        int row = rowbase + rl;
        __syncthreads();
        {
            float4 v = make_float4(0.f, 0.f, 0.f, 0.f);
            if (row < n) v = reinterpret_cast<const float4*>(X)[(size_t)row * 16 + c4];
            *reinterpret_cast<float4*>(&Xs[rl][c4 * 4]) = v;
        }
        __syncthreads();

        float4 acc = make_float4(0.f, 0.f, 0.f, 0.f);
#pragma unroll
        for (int k = 0; k < D; ++k) {
            float xk = Xs[rl][k];
            float4 w = *reinterpret_cast<const float4*>(&Ws[k][c4 * 4]);
            acc.x += xk * w.x;
            acc.y += xk * w.y;
            acc.z += xk * w.z;
            acc.w += xk * w.w;
        }
        if (row < n) {
            float dv = dinv[row];
            __half2 h01 = __floats2half2_rn(acc.x * dv, acc.y * dv);
            __half2 h23 = __floats2half2_rn(acc.z * dv, acc.w * dv);
            int2 packed;
            packed.x = *reinterpret_cast<int*>(&h01);
            packed.y = *reinterpret_cast<int*>(&h23);
            reinterpret_cast<int2*>(G)[(size_t)row * 16 + c4] = packed;
        }
    }
}

// out[i] = dinv[i]*(G[i] + sum_{src in row i} G[src]) + b ; optional relu.
// One wave per row; lane = (eq = lane>>4 edge subgroup, c4 = lane&15).
// Each lane gathers 8B (4 halves) per edge; 16 lanes cover the 128B fp16 row.
__global__ __launch_bounds__(256) void k_agg2(const __half* __restrict__ G,
                                              const int* __restrict__ rowptr,
                                              const int* __restrict__ csr,
                                              const float* __restrict__ dinv,
                                              const float* __restrict__ bias,
                                              float* __restrict__ out,
                                              int n, int do_relu) {
    int wid = (blockIdx.x * blockDim.x + threadIdx.x) >> 6;
    if (wid >= n) return;
    int lane = threadIdx.x & 63;
    int eq = lane >> 4;
    int c4 = lane & 15;
    int beg = rowptr[wid];
    int end = rowptr[wid + 1];

    float4 acc = make_float4(0.f, 0.f, 0.f, 0.f);
    for (int e = beg + eq; e < end; e += 4) {
        int s = __builtin_nontemporal_load(&csr[e]);
        int2 raw = reinterpret_cast<const int2*>(G)[(size_t)s * 16 + c4];
        __half2 p0 = *reinterpret_cast<__half2*>(&raw.x);
        __half2 p1 = *reinterpret_cast<__half2*>(&raw.y);
        float2 f0 = __half22float2(p0);
        float2 f1 = __half22float2(p1);
        acc.x += f0.x; acc.y += f0.y; acc.z += f1.x; acc.w += f1.y;
    }
#pragma unroll
    for (int off = 16; off < 64; off <<= 1) {
        acc.x += __shfl_xor(acc.x, off);
        acc.y += __shfl_xor(acc.y, off);
        acc.z += __shfl_xor(acc.z, off);
        acc.w += __shfl_xor(acc.w, off);
    }
    if (eq == 0) {
        int2 raw = reinterpret_cast<const int2*>(G)[(size_t)wid * 16 + c4];
        __half2 p0 = *reinterpret_cast<__half2*>(&raw.x);
        __half2 p1 = *reinterpret_cast<__half2*>(&raw.y);
        float2 f0 = __half22float2(p0);
        float2 f1 = __half22float2(p1);
        float dv = dinv[wid];
        float4 b4 = reinterpret_cast<const float4*>(bias)[c4];
        float4 o;
        o.x = (acc.x + f0.x) * dv + b4.x;
        o.y = (acc.y + f0.y) * dv + b4.y;
        o.z = (acc.z + f1.x) * dv + b4.z;
        o.w = (acc.w + f1.y) * dv + b4.w;
        if (do_relu) {
            o.x = fmaxf(o.x, 0.f); o.y = fmaxf(o.y, 0.f);
            o.z = fmaxf(o.z, 0.f); o.w = fmaxf(o.w, 0.f);
        }
        reinterpret_cast<float4*>(out)[(size_t)wid * 16 + c4] = o;
    }
}

// ---------------- launch ----------------

extern "C" void kernel_launch(void* const* d_in, const int* in_sizes, int n_in,
                              void* d_out, int out_size, void* d_ws, size_t ws_size,
                              hipStream_t stream) {
    const int* ei = (const int*)d_in[0];
    const float* emb = (const float*)d_in[1];
    const float* W1 = (const float*)d_in[2];
    const float* b1 = (const float*)d_in[3];
    const float* W2 = (const float*)d_in[4];
    const float* b2 = (const float*)d_in[5];
    float* out = (float*)d_out;

    int E = in_sizes[0] / 2;
    int N = in_sizes[1] / D;
    const int* src = ei;
    const int* dst = ei + E;

    auto al = [](size_t x) { return (x + 255) & ~(size_t)255; };
    char* ws = (char*)d_ws;
    size_t off = 0;
    int* cnt = (int*)(ws + off);      off = al(off + (size_t)N * 4);
    int* rowptr = (int*)(ws + off);   off = al(off + ((size_t)N + 1) * 4);
    int* cursor = (int*)(ws + off);   off = al(off + (size_t)N * 4);
    int* bsums = (int*)(ws + off);    off = al(off + 64 * 4);
    int* csr = (int*)(ws + off);      off = al(off + (size_t)E * 4);
    float* dinv = (float*)(ws + off); off = al(off + (size_t)N * 4);
    __half* g = (__half*)(ws + off);  off = al(off + (size_t)N * D * 2);
    float* x = out;  // reuse d_out as the layer-1 activation buffer

    int nb_scan = (N + 2047) / 2048;
    int ntiles = (N + 15) / 16;
    int gemm_blocks = 1024;
    int part_blocks = 1024;  // 8 ranges x 128 chunks

    hipLaunchKernelGGL(k_zero, dim3(512), dim3(256), 0, stream, cnt, (N + 3) / 4);
    hipLaunchKernelGGL(k_hist, dim3(part_blocks), dim3(256), 0, stream, dst, cnt, E, N);
    hipLaunchKernelGGL(k_scan1, dim3(nb_scan), dim3(256), 0, stream, cnt, rowptr, bsums, N);
    hipLaunchKernelGGL(k_scan2, dim3((N + 255) / 256), dim3(256), 0, stream,
                       rowptr, cursor, dinv, cnt, bsums, N, nb_scan);
    hipLaunchKernelGGL(k_fill, dim3(part_blocks), dim3(256), 0, stream,
                       src, dst, cursor, csr, E, N);

    // layer 1
    hipLaunchKernelGGL(k_gemm2, dim3(gemm_blocks), dim3(256), 0, stream,
                       emb, W1, dinv, g, N, ntiles);
    hipLaunchKernelGGL(k_agg2, dim3((N + 3) / 4), dim3(256), 0, stream,
                       g, rowptr, csr, dinv, b1, x, N, 1);

    // layer 2
    hipLaunchKernelGGL(k_gemm2, dim3(gemm_blocks), dim3(256), 0, stream,
                       x, W2, dinv, g, N, ntiles);
    hipLaunchKernelGGL(k_agg2, dim3((N + 3) / 4), dim3(256), 0, stream,
                       g, rowptr, csr, dinv, b2, out, N, 0);
}

// Round 9
// 180.966 us; speedup vs baseline: 1.2661x; 1.0663x over previous
//
#include <hip/hip_runtime.h>
#include <hip/hip_fp16.h>

#define D 64

// ---------------- CSR build ----------------
// k_hist / fill partition the dst space 8 ways by blockIdx.x&7 (XCD-local
// line ownership; unpartitioned scatter measured 64B writeback per 4B store).

__global__ __launch_bounds__(256) void k_zero(int* __restrict__ p, int n4) {
    int stride = gridDim.x * blockDim.x;
    for (int i = blockIdx.x * blockDim.x + threadIdx.x; i < n4; i += stride)
        reinterpret_cast<int4*>(p)[i] = make_int4(0, 0, 0, 0);
}

__global__ __launch_bounds__(256) void k_hist(const int* __restrict__ dst,
                                              int* __restrict__ cnt, int e, int n) {
    int r = blockIdx.x & 7;
    int lo = (int)(((long long)r * n) >> 3);
    int hi = (int)(((long long)(r + 1) * n) >> 3);
    int nch = gridDim.x >> 3;
    int chunk = blockIdx.x >> 3;
    for (int i = chunk * blockDim.x + threadIdx.x; i < e; i += nch * blockDim.x) {
        int d = dst[i];
        if (d >= lo && d < hi) atomicAdd(&cnt[d], 1);
    }
}

__global__ void k_scan1(const int* __restrict__ cnt, int* __restrict__ rowptr,
                        int* __restrict__ bsums, int n) {
    __shared__ int lds[256];
    int tid = threadIdx.x;
    int base = blockIdx.x * 2048 + tid * 8;
    int v[8];
    int s = 0;
#pragma unroll
    for (int j = 0; j < 8; ++j) {
        int idx = base + j;
        v[j] = (idx < n) ? cnt[idx] : 0;
        s += v[j];
    }
    lds[tid] = s;
    __syncthreads();
    for (int off = 1; off < 256; off <<= 1) {
        int t = (tid >= off) ? lds[tid - off] : 0;
        __syncthreads();
        lds[tid] += t;
        __syncthreads();
    }
    int run = lds[tid] - s;
#pragma unroll
    for (int j = 0; j < 8; ++j) {
        int idx = base + j;
        if (idx < n) rowptr[idx] = run;
        run += v[j];
    }
    if (tid == 255) bsums[blockIdx.x] = lds[255];
}

__global__ void k_scan2(int* __restrict__ rowptr, int* __restrict__ cursor,
                        float* __restrict__ dinv, const int* __restrict__ cnt,
                        const int* __restrict__ bsums, int n, int nb) {
    __shared__ int s_off;
    int i = blockIdx.x * blockDim.x + threadIdx.x;
    int b = (blockIdx.x * blockDim.x) >> 11;
    if (threadIdx.x == 0) {
        int o = 0;
        for (int j = 0; j < b; ++j) o += bsums[j];
        s_off = o;
    }
    __syncthreads();
    if (i < n) {
        int rp = rowptr[i] + s_off;
        rowptr[i] = rp;
        cursor[i] = rp;
        dinv[i] = rsqrtf((float)(cnt[i] + 1));
    }
    if (blockIdx.x == 0 && threadIdx.x == 0) {
        int t = 0;
        for (int j = 0; j < nb; ++j) t += bsums[j];
        rowptr[n] = t;
    }
}

// ---------------- fused fill || gemm1 ----------------
// Blocks [0, fill_blocks) scatter-fill the CSR (8-way XCD partitioned);
// blocks [fill_blocks, gridDim) compute G1 = (emb @ W1) * dinv in fp16.
// The two stages are independent (both depend only on scan2); merging them
// into one launch lets them overlap inside the serialized capture stream.
__global__ __launch_bounds__(256) void k_fill_gemm(
    const int* __restrict__ src, const int* __restrict__ dst,
    int* __restrict__ cursor, int* __restrict__ csr, int e, int n,
    const float* __restrict__ X, const float* __restrict__ W,
    const float* __restrict__ dinv, __half* __restrict__ G,
    int ntiles, int fill_blocks) {
    __shared__ float Ws[D][D];       // 16 KB
    __shared__ float Xs[16][D + 4];

    if (blockIdx.x < fill_blocks) {  // ---- fill path (no LDS, no barriers)
        int r = blockIdx.x & 7;
        int lo = (int)(((long long)r * n) >> 3);
        int hi = (int)(((long long)(r + 1) * n) >> 3);
        int nch = fill_blocks >> 3;
        int chunk = blockIdx.x >> 3;
        for (int i = chunk * blockDim.x + threadIdx.x; i < e; i += nch * blockDim.x) {
            int d = dst[i];
            if (d >= lo && d < hi) {
                int pos = atomicAdd(&cursor[d], 1);
                csr[pos] = src[i];
            }
        }
        return;
    }

    // ---- gemm path
    int tid = threadIdx.x;
    int rl = tid >> 4;
    int c4 = tid & 15;
    int gb = blockIdx.x - fill_blocks;
    int ngb = gridDim.x - fill_blocks;

    for (int i = tid; i < (D * D) / 4; i += 256)
        reinterpret_cast<float4*>(&Ws[0][0])[i] = reinterpret_cast<const float4*>(W)[i];

    for (int tile = gb; tile < ntiles; tile += ngb) {
        int row = tile * 16 + rl;
        __syncthreads();
        {
            float4 v = make_float4(0.f, 0.f, 0.f, 0.f);
            if (row < n) v = reinterpret_cast<const float4*>(X)[(size_t)row * 16 + c4];
            *reinterpret_cast<float4*>(&Xs[rl][c4 * 4]) = v;
        }
        __syncthreads();

        float4 acc = make_float4(0.f, 0.f, 0.f, 0.f);
#pragma unroll
        for (int k = 0; k < D; ++k) {
            float xk = Xs[rl][k];
            float4 w = *reinterpret_cast<const float4*>(&Ws[k][c4 * 4]);
            acc.x += xk * w.x; acc.y += xk * w.y;
            acc.z += xk * w.z; acc.w += xk * w.w;
        }
        if (row < n) {
            float dv = dinv[row];
            __half2 h01 = __floats2half2_rn(acc.x * dv, acc.y * dv);
            __half2 h23 = __floats2half2_rn(acc.z * dv, acc.w * dv);
            int2 packed;
            packed.x = *reinterpret_cast<int*>(&h01);
            packed.y = *reinterpret_cast<int*>(&h23);
            reinterpret_cast<int2*>(G)[(size_t)row * 16 + c4] = packed;
        }
    }
}

// ---------------- fused agg1 + gemm2 ----------------
// One wave per row r: gather-sum G1[src] rows, add self, scale, +b1, relu
// (x stays in registers), then immediately g2[r] = dinv[r] * (x @ W2) via LDS.
// x is never materialized in HBM (-25.6 MB round trip, -1 launch).
__global__ __launch_bounds__(256) void k_agg_gemm(
    const __half* __restrict__ G1, const int* __restrict__ rowptr,
    const int* __restrict__ csr, const float* __restrict__ dinv,
    const float* __restrict__ b1, const float* __restrict__ W2,
    __half* __restrict__ G2, int n) {
    __shared__ float W2s[D][D];      // 16 KB
    __shared__ float xs[4][D];       // per-wave x row
    int tid = threadIdx.x;

    for (int i = tid; i < (D * D) / 4; i += 256)
        reinterpret_cast<float4*>(&W2s[0][0])[i] = reinterpret_cast<const float4*>(W2)[i];

    int wv = tid >> 6;
    int lane = tid & 63;
    int eq = lane >> 4;
    int c4 = lane & 15;
    int wid = blockIdx.x * 4 + wv;
    if (wid >= n) wid = n - 1;  // clamp: duplicate waves redo row n-1 (benign)

    int beg = rowptr[wid];
    int end = rowptr[wid + 1];
    float4 acc = make_float4(0.f, 0.f, 0.f, 0.f);
    for (int e = beg + eq; e < end; e += 4) {
        int s = __builtin_nontemporal_load(&csr[e]);
        int2 raw = reinterpret_cast<const int2*>(G1)[(size_t)s * 16 + c4];
        __half2 p0 = *reinterpret_cast<__half2*>(&raw.x);
        __half2 p1 = *reinterpret_cast<__half2*>(&raw.y);
        float2 f0 = __half22float2(p0);
        float2 f1 = __half22float2(p1);
        acc.x += f0.x; acc.y += f0.y; acc.z += f1.x; acc.w += f1.y;
    }
#pragma unroll
    for (int off = 16; off < 64; off <<= 1) {
        acc.x += __shfl_xor(acc.x, off);
        acc.y += __shfl_xor(acc.y, off);
        acc.z += __shfl_xor(acc.z, off);
        acc.w += __shfl_xor(acc.w, off);
    }
    // x quad = relu((gather + self) * dinv + b1)
    int2 rawS = reinterpret_cast<const int2*>(G1)[(size_t)wid * 16 + c4];
    __half2 s0 = *reinterpret_cast<__half2*>(&rawS.x);
    __half2 s1 = *reinterpret_cast<__half2*>(&rawS.y);
    float2 g0 = __half22float2(s0);
    float2 g1v = __half22float2(s1);
    float dv = dinv[wid];
    float4 b4 = reinterpret_cast<const float4*>(b1)[c4];
    float4 xq;
    xq.x = fmaxf((acc.x + g0.x) * dv + b4.x, 0.f);
    xq.y = fmaxf((acc.y + g0.y) * dv + b4.y, 0.f);
    xq.z = fmaxf((acc.z + g1v.x) * dv + b4.z, 0.f);
    xq.w = fmaxf((acc.w + g1v.y) * dv + b4.w, 0.f);

    __syncthreads();  // W2s staged; all waves present (wid clamped, no returns)
    if (eq == 0) *reinterpret_cast<float4*>(&xs[wv][c4 * 4]) = xq;
    __syncthreads();  // xs visible

    // g2[r][lane] = dinv[r] * sum_k x[k] * W2[k][lane]
    float a2 = 0.f;
#pragma unroll
    for (int k4 = 0; k4 < D; k4 += 4) {
        float4 xv = *reinterpret_cast<const float4*>(&xs[wv][k4]);  // broadcast
        a2 += xv.x * W2s[k4 + 0][lane];
        a2 += xv.y * W2s[k4 + 1][lane];
        a2 += xv.z * W2s[k4 + 2][lane];
        a2 += xv.w * W2s[k4 + 3][lane];
    }
    G2[(size_t)wid * D + lane] = __float2half(a2 * dv);
}

// ---------------- final aggregation (layer 2) ----------------
__global__ __launch_bounds__(256) void k_agg2(const __half* __restrict__ G,
                                              const int* __restrict__ rowptr,
                                              const int* __restrict__ csr,
                                              const float* __restrict__ dinv,
                                              const float* __restrict__ bias,
                                              float* __restrict__ out, int n) {
    int wid = (blockIdx.x * blockDim.x + threadIdx.x) >> 6;
    if (wid >= n) return;
    int lane = threadIdx.x & 63;
    int eq = lane >> 4;
    int c4 = lane & 15;
    int beg = rowptr[wid];
    int end = rowptr[wid + 1];

    float4 acc = make_float4(0.f, 0.f, 0.f, 0.f);
    for (int e = beg + eq; e < end; e += 4) {
        int s = __builtin_nontemporal_load(&csr[e]);
        int2 raw = reinterpret_cast<const int2*>(G)[(size_t)s * 16 + c4];
        __half2 p0 = *reinterpret_cast<__half2*>(&raw.x);
        __half2 p1 = *reinterpret_cast<__half2*>(&raw.y);
        float2 f0 = __half22float2(p0);
        float2 f1 = __half22float2(p1);
        acc.x += f0.x; acc.y += f0.y; acc.z += f1.x; acc.w += f1.y;
    }
#pragma unroll
    for (int off = 16; off < 64; off <<= 1) {
        acc.x += __shfl_xor(acc.x, off);
        acc.y += __shfl_xor(acc.y, off);
        acc.z += __shfl_xor(acc.z, off);
        acc.w += __shfl_xor(acc.w, off);
    }
    if (eq == 0) {
        int2 raw = reinterpret_cast<const int2*>(G)[(size_t)wid * 16 + c4];
        __half2 p0 = *reinterpret_cast<__half2*>(&raw.x);
        __half2 p1 = *reinterpret_cast<__half2*>(&raw.y);
        float2 f0 = __half22float2(p0);
        float2 f1 = __half22float2(p1);
        float dv = dinv[wid];
        float4 b4 = reinterpret_cast<const float4*>(bias)[c4];
        float4 o;
        o.x = (acc.x + f0.x) * dv + b4.x;
        o.y = (acc.y + f0.y) * dv + b4.y;
        o.z = (acc.z + f1.x) * dv + b4.z;
        o.w = (acc.w + f1.y) * dv + b4.w;
        reinterpret_cast<float4*>(out)[(size_t)wid * 16 + c4] = o;
    }
}

// ---------------- launch ----------------

extern "C" void kernel_launch(void* const* d_in, const int* in_sizes, int n_in,
                              void* d_out, int out_size, void* d_ws, size_t ws_size,
                              hipStream_t stream) {
    const int* ei = (const int*)d_in[0];
    const float* emb = (const float*)d_in[1];
    const float* W1 = (const float*)d_in[2];
    const float* b1 = (const float*)d_in[3];
    const float* W2 = (const float*)d_in[4];
    const float* b2 = (const float*)d_in[5];
    float* out = (float*)d_out;

    int E = in_sizes[0] / 2;
    int N = in_sizes[1] / D;
    const int* src = ei;
    const int* dst = ei + E;

    auto al = [](size_t x) { return (x + 255) & ~(size_t)255; };
    char* ws = (char*)d_ws;
    size_t off = 0;
    int* cnt = (int*)(ws + off);      off = al(off + (size_t)N * 4);
    int* rowptr = (int*)(ws + off);   off = al(off + ((size_t)N + 1) * 4);
    int* cursor = (int*)(ws + off);   off = al(off + (size_t)N * 4);
    int* bsums = (int*)(ws + off);    off = al(off + 64 * 4);
    int* csr = (int*)(ws + off);      off = al(off + (size_t)E * 4);
    float* dinv = (float*)(ws + off); off = al(off + (size_t)N * 4);
    __half* g1 = (__half*)(ws + off); off = al(off + (size_t)N * D * 2);
    __half* g2 = (__half*)(ws + off); off = al(off + (size_t)N * D * 2);

    int nb_scan = (N + 2047) / 2048;
    int ntiles = (N + 15) / 16;
    int fill_blocks = 1024;   // 8 ranges x 128 chunks
    int gemm_blocks = 1024;
    int row_blocks = (N + 3) / 4;  // one wave per row, 4 waves/block

    hipLaunchKernelGGL(k_zero, dim3(512), dim3(256), 0, stream, cnt, (N + 3) / 4);
    hipLaunchKernelGGL(k_hist, dim3(1024), dim3(256), 0, stream, dst, cnt, E, N);
    hipLaunchKernelGGL(k_scan1, dim3(nb_scan), dim3(256), 0, stream, cnt, rowptr, bsums, N);
    hipLaunchKernelGGL(k_scan2, dim3((N + 255) / 256), dim3(256), 0, stream,
                       rowptr, cursor, dinv, cnt, bsums, N, nb_scan);
    hipLaunchKernelGGL(k_fill_gemm, dim3(fill_blocks + gemm_blocks), dim3(256), 0, stream,
                       src, dst, cursor, csr, E, N, emb, W1, dinv, g1, ntiles, fill_blocks);
    hipLaunchKernelGGL(k_agg_gemm, dim3(row_blocks), dim3(256), 0, stream,
                       g1, rowptr, csr, dinv, b1, W2, g2, N);
    hipLaunchKernelGGL(k_agg2, dim3(row_blocks), dim3(256), 0, stream,
                       g2, rowptr, csr, dinv, b2, out, N);
}